// Round 2
// baseline (947.856 us; speedup 1.0000x reference)
//
#include <hip/hip_runtime.h>
#include <math.h>

#define BB 2
#define LL 4096
#define DD 512
#define HH 8
#define DKK 64

// ---------------------------------------------------------------------------
// proj_kernel: Y = X[M=8192, 512] @ W[512,512] + bias, fp32.
// 64x64 output tile, BK=16, 256 threads, 4x4 per thread.
// split_heads=1: write Y as [B, H, L, DK] (head-split). else flat [M, 512].
// LDS: As transposed [k][m] so inner reads are ds_read_b128, pad 68 keeps
// 16B alignment (68*4=272 bytes/row) and <=2-way bank conflicts.
// ---------------------------------------------------------------------------
__global__ __launch_bounds__(256) void proj_kernel(
    const float* __restrict__ X, const float* __restrict__ W,
    const float* __restrict__ bias, float* __restrict__ Y, int split_heads)
{
    __shared__ float As[16][68];
    __shared__ float Bs[16][68];

    const int tid = threadIdx.x;
    const int tr = tid >> 4;          // 0..15
    const int tc = tid & 15;          // 0..15
    const int m0 = blockIdx.x * 64;
    const int n0 = blockIdx.y * 64;

    const int ar = tid >> 2;          // A-load row within tile (0..63)
    const int ak = (tid & 3) << 2;    // A-load k within tile (0,4,8,12)
    const int bk = tid >> 4;          // B-load k within tile (0..15)
    const int bn = (tid & 15) << 2;   // B-load n within tile

    float acc[4][4] = {};

    for (int k0 = 0; k0 < DD; k0 += 16) {
        float4 av = *(const float4*)&X[(size_t)(m0 + ar) * DD + k0 + ak];
        float4 bv = *(const float4*)&W[(size_t)(k0 + bk) * DD + n0 + bn];
        As[ak + 0][ar] = av.x;
        As[ak + 1][ar] = av.y;
        As[ak + 2][ar] = av.z;
        As[ak + 3][ar] = av.w;
        *(float4*)&Bs[bk][bn] = bv;
        __syncthreads();
#pragma unroll
        for (int k = 0; k < 16; ++k) {
            float4 a4 = *(const float4*)&As[k][tr << 2];
            float4 b4 = *(const float4*)&Bs[k][tc << 2];
            float a[4] = {a4.x, a4.y, a4.z, a4.w};
            float b[4] = {b4.x, b4.y, b4.z, b4.w};
#pragma unroll
            for (int i = 0; i < 4; ++i)
#pragma unroll
                for (int j = 0; j < 4; ++j)
                    acc[i][j] = fmaf(a[i], b[j], acc[i][j]);
        }
        __syncthreads();
    }

    float4 bv4 = *(const float4*)&bias[n0 + (tc << 2)];
    const float bb[4] = {bv4.x, bv4.y, bv4.z, bv4.w};

    if (!split_heads) {
#pragma unroll
        for (int i = 0; i < 4; ++i) {
            int row = m0 + (tr << 2) + i;
            float4 o = make_float4(acc[i][0] + bb[0], acc[i][1] + bb[1],
                                   acc[i][2] + bb[2], acc[i][3] + bb[3]);
            *(float4*)&Y[(size_t)row * DD + n0 + (tc << 2)] = o;
        }
    } else {
        const int col = n0 + (tc << 2);
        const int h  = col >> 6;      // constant per block (n0 % 64 == 0)
        const int dk = col & 63;
#pragma unroll
        for (int i = 0; i < 4; ++i) {
            int row = m0 + (tr << 2) + i;     // = b*L + l
            int b_  = row >> 12;              // L = 4096
            int l_  = row & (LL - 1);
            float4 o = make_float4(acc[i][0] + bb[0], acc[i][1] + bb[1],
                                   acc[i][2] + bb[2], acc[i][3] + bb[3]);
            *(float4*)&Y[((((size_t)b_ * HH + h) * LL) + l_) * DKK + dk] = o;
        }
    }
}

// ---------------------------------------------------------------------------
// flash_kernel: causal flash attention, fp32.
// One block = one (b,h, 64-row q-tile). 256 threads (16x16, 4x4 frags).
// LDS: Qs [dk][row] (transposed), KPs [dk][col] for K then aliased as
// P [row][kv] after S-GEMM, Vs [kv][dk] natural. Pad 68 words/row.
// Online softmax in registers; 16-lane shfl_xor row reductions.
// ---------------------------------------------------------------------------
__global__ __launch_bounds__(256) void flash_kernel(
    const float* __restrict__ qh, const float* __restrict__ kh,
    const float* __restrict__ vh, float* __restrict__ ctx)
{
    __shared__ float Qs[64][68];
    __shared__ float KPs[64][68];
    __shared__ float Vs[64][68];

    const int tid = threadIdx.x;
    const int tr = tid >> 4;          // 0..15
    const int tc = tid & 15;          // 0..15
    const int bh = blockIdx.x;        // b*H + h
    const int qt = (int)gridDim.y - 1 - (int)blockIdx.y;  // heavy tiles first

    const float* qbase = qh + (size_t)bh * LL * DKK;
    const float* kbase = kh + (size_t)bh * LL * DKK;
    const float* vbase = vh + (size_t)bh * LL * DKK;

    // Load Q tile, transposed into Qs[dk][row]
#pragma unroll
    for (int i = 0; i < 4; ++i) {
        int f = tid + i * 256;        // 0..1023
        int r = f >> 4;               // 0..63
        int c = (f & 15) << 2;        // 0..60
        float4 v4 = *(const float4*)&qbase[(size_t)(qt * 64 + r) * DKK + c];
        Qs[c + 0][r] = v4.x; Qs[c + 1][r] = v4.y;
        Qs[c + 2][r] = v4.z; Qs[c + 3][r] = v4.w;
    }

    float O[4][4] = {};
    float mprev[4] = {-1e30f, -1e30f, -1e30f, -1e30f};
    float lsum[4] = {0.f, 0.f, 0.f, 0.f};
    const float scale = 0.125f;       // 1/sqrt(64)

    for (int kt = 0; kt <= qt; ++kt) {
        __syncthreads();  // previous PV done; also covers initial Q store
        // Load K (transposed) and V (natural) tiles
#pragma unroll
        for (int i = 0; i < 4; ++i) {
            int f = tid + i * 256;
            int r = f >> 4;
            int c = (f & 15) << 2;
            float4 k4 = *(const float4*)&kbase[(size_t)(kt * 64 + r) * DKK + c];
            KPs[c + 0][r] = k4.x; KPs[c + 1][r] = k4.y;
            KPs[c + 2][r] = k4.z; KPs[c + 3][r] = k4.w;
            float4 v4 = *(const float4*)&vbase[(size_t)(kt * 64 + r) * DKK + c];
            *(float4*)&Vs[r][c] = v4;
        }
        __syncthreads();

        // S = scale * Q K^T   (s[i][j]: row 4tr+i, col 4tc+j)
        float s[4][4] = {};
#pragma unroll 16
        for (int k = 0; k < 64; ++k) {
            float4 a4 = *(const float4*)&Qs[k][tr << 2];
            float4 b4 = *(const float4*)&KPs[k][tc << 2];
            float a[4] = {a4.x, a4.y, a4.z, a4.w};
            float b[4] = {b4.x, b4.y, b4.z, b4.w};
#pragma unroll
            for (int i = 0; i < 4; ++i)
#pragma unroll
                for (int j = 0; j < 4; ++j)
                    s[i][j] = fmaf(a[i], b[j], s[i][j]);
        }

#pragma unroll
        for (int i = 0; i < 4; ++i)
#pragma unroll
            for (int j = 0; j < 4; ++j)
                s[i][j] *= scale;

        if (kt == qt) {  // diagonal tile: mask col > row (local coords)
#pragma unroll
            for (int i = 0; i < 4; ++i) {
                int R = (tr << 2) + i;
#pragma unroll
                for (int j = 0; j < 4; ++j) {
                    int C = (tc << 2) + j;
                    if (C > R) s[i][j] = -1e30f;
                }
            }
        }

        // Row max over this tile (4 local + 16-lane butterfly)
        float rmax[4];
#pragma unroll
        for (int i = 0; i < 4; ++i)
            rmax[i] = fmaxf(fmaxf(s[i][0], s[i][1]), fmaxf(s[i][2], s[i][3]));
#pragma unroll
        for (int off = 1; off < 16; off <<= 1)
#pragma unroll
            for (int i = 0; i < 4; ++i)
                rmax[i] = fmaxf(rmax[i], __shfl_xor(rmax[i], off));

        // Online softmax update (all per-register; values replicated in group)
        float rsum[4];
#pragma unroll
        for (int i = 0; i < 4; ++i) {
            float mnew = fmaxf(mprev[i], rmax[i]);
            float f = __expf(mprev[i] - mnew);
            mprev[i] = mnew;
            float rs = 0.f;
#pragma unroll
            for (int j = 0; j < 4; ++j) {
                s[i][j] = __expf(s[i][j] - mnew);
                rs += s[i][j];
            }
            rsum[i] = rs;
            lsum[i] *= f;
#pragma unroll
            for (int j = 0; j < 4; ++j) O[i][j] *= f;
        }
#pragma unroll
        for (int off = 1; off < 16; off <<= 1)
#pragma unroll
            for (int i = 0; i < 4; ++i)
                rsum[i] += __shfl_xor(rsum[i], off);
#pragma unroll
        for (int i = 0; i < 4; ++i) lsum[i] += rsum[i];

        __syncthreads();  // everyone done reading K from KPs
        // Store P into KPs as [row][kv]
#pragma unroll
        for (int i = 0; i < 4; ++i)
            *(float4*)&KPs[(tr << 2) + i][tc << 2] =
                make_float4(s[i][0], s[i][1], s[i][2], s[i][3]);
        __syncthreads();

        // O += P @ V   (A = KPs[row][kv], B = Vs[kv][dk])
#pragma unroll 4
        for (int kk = 0; kk < 16; ++kk) {
            float a[4][4], b[4][4];
#pragma unroll
            for (int i = 0; i < 4; ++i) {
                float4 a4 = *(const float4*)&KPs[(tr << 2) + i][kk << 2];
                a[i][0] = a4.x; a[i][1] = a4.y; a[i][2] = a4.z; a[i][3] = a4.w;
            }
#pragma unroll
            for (int kq = 0; kq < 4; ++kq) {
                float4 b4 = *(const float4*)&Vs[(kk << 2) + kq][tc << 2];
                b[kq][0] = b4.x; b[kq][1] = b4.y; b[kq][2] = b4.z; b[kq][3] = b4.w;
            }
#pragma unroll
            for (int i = 0; i < 4; ++i)
#pragma unroll
                for (int kq = 0; kq < 4; ++kq)
#pragma unroll
                    for (int j = 0; j < 4; ++j)
                        O[i][j] = fmaf(a[i][kq], b[kq][j], O[i][j]);
        }
    }

    // Epilogue: normalize and write ctx[b][l][h*64 + dk]
    const int b_ = bh >> 3;
    const int h_ = bh & 7;
#pragma unroll
    for (int i = 0; i < 4; ++i) {
        float inv = 1.0f / lsum[i];
        int l_ = qt * 64 + (tr << 2) + i;
        float4 o = make_float4(O[i][0] * inv, O[i][1] * inv,
                               O[i][2] * inv, O[i][3] * inv);
        *(float4*)&ctx[((size_t)b_ * LL + l_) * DD + h_ * DKK + (tc << 2)] = o;
    }
}

// ---------------------------------------------------------------------------
extern "C" void kernel_launch(void* const* d_in, const int* in_sizes, int n_in,
                              void* d_out, int out_size, void* d_ws, size_t ws_size,
                              hipStream_t stream) {
    const float* q  = (const float*)d_in[0];
    const float* k  = (const float*)d_in[1];
    const float* v  = (const float*)d_in[2];
    // d_in[3] = causal mask (tril) — semantics hard-coded in flash_kernel
    const float* Wq = (const float*)d_in[4];
    const float* bq = (const float*)d_in[5];
    const float* Wk = (const float*)d_in[6];
    const float* bk = (const float*)d_in[7];
    const float* Wv = (const float*)d_in[8];
    const float* bv = (const float*)d_in[9];
    const float* Wo = (const float*)d_in[10];
    const float* bo = (const float*)d_in[11];
    float* out = (float*)d_out;

    float* ws = (float*)d_ws;
    const size_t nBH = (size_t)BB * HH * LL * DKK;   // 4,194,304 floats
    float* qh  = ws;
    float* kh  = qh + nBH;
    float* vh  = kh + nBH;
    float* ctx = vh + nBH;

    dim3 pg(128, 8), pb(256);
    proj_kernel<<<pg, pb, 0, stream>>>(q, Wq, bq, qh, 1);
    proj_kernel<<<pg, pb, 0, stream>>>(k, Wk, bk, kh, 1);
    proj_kernel<<<pg, pb, 0, stream>>>(v, Wv, bv, vh, 1);

    flash_kernel<<<dim3(16, 64), 256, 0, stream>>>(qh, kh, vh, ctx);

    proj_kernel<<<pg, pb, 0, stream>>>(ctx, Wo, bo, out, 0);
}

// Round 10
// 467.801 us; speedup vs baseline: 2.0262x; 2.0262x over previous
//
#include <hip/hip_runtime.h>
#include <hip/hip_bf16.h>
#include <math.h>

#define BB 2
#define LL 4096
#define DD 512
#define HH 8
#define DKK 64

typedef short bf16x8 __attribute__((ext_vector_type(8)));   // 8 bf16 in 4 VGPRs
typedef float f32x4 __attribute__((ext_vector_type(4)));

__device__ __forceinline__ unsigned short f2bf(float x) {
    __hip_bfloat16 h = __float2bfloat16(x);
    return *reinterpret_cast<unsigned short*>(&h);
}

// ---------------------------------------------------------------------------
// proj_kernel: Y = X[M=8192, 512] @ W[512,512] + bias, fp32 compute.
// mode 0: f32 flat [M][512]        (final output projection)
// mode 1: bf16 [b,h,l,dk]          (q, k)
// mode 2: bf16 transposed [b,h,dk,l] via LDS transpose (v)
// ---------------------------------------------------------------------------
__global__ __launch_bounds__(256) void proj_kernel(
    const float* __restrict__ X, const float* __restrict__ W,
    const float* __restrict__ bias, float* __restrict__ Yf,
    unsigned short* __restrict__ Ybf, int mode)
{
    __shared__ float As[16][68];
    __shared__ float Bs[16][68];
    __shared__ unsigned short T[64][72];   // for mode 2 transpose

    const int tid = threadIdx.x;
    const int tr = tid >> 4;          // 0..15
    const int tc = tid & 15;          // 0..15
    const int m0 = blockIdx.x * 64;
    const int n0 = blockIdx.y * 64;

    const int ar = tid >> 2;          // A-load row within tile (0..63)
    const int ak = (tid & 3) << 2;    // A-load k within tile
    const int bk = tid >> 4;          // B-load k within tile (0..15)
    const int bn = (tid & 15) << 2;   // B-load n within tile

    float acc[4][4] = {};

    for (int k0 = 0; k0 < DD; k0 += 16) {
        float4 av = *(const float4*)&X[(size_t)(m0 + ar) * DD + k0 + ak];
        float4 bv = *(const float4*)&W[(size_t)(k0 + bk) * DD + n0 + bn];
        As[ak + 0][ar] = av.x;
        As[ak + 1][ar] = av.y;
        As[ak + 2][ar] = av.z;
        As[ak + 3][ar] = av.w;
        *(float4*)&Bs[bk][bn] = bv;
        __syncthreads();
#pragma unroll
        for (int k = 0; k < 16; ++k) {
            float4 a4 = *(const float4*)&As[k][tr << 2];
            float4 b4 = *(const float4*)&Bs[k][tc << 2];
            float a[4] = {a4.x, a4.y, a4.z, a4.w};
            float b[4] = {b4.x, b4.y, b4.z, b4.w};
#pragma unroll
            for (int i = 0; i < 4; ++i)
#pragma unroll
                for (int j = 0; j < 4; ++j)
                    acc[i][j] = fmaf(a[i], b[j], acc[i][j]);
        }
        __syncthreads();
    }

    float4 bv4 = *(const float4*)&bias[n0 + (tc << 2)];
    const float bb[4] = {bv4.x, bv4.y, bv4.z, bv4.w};

    if (mode == 0) {
#pragma unroll
        for (int i = 0; i < 4; ++i) {
            int row = m0 + (tr << 2) + i;
            float4 o = make_float4(acc[i][0] + bb[0], acc[i][1] + bb[1],
                                   acc[i][2] + bb[2], acc[i][3] + bb[3]);
            *(float4*)&Yf[(size_t)row * DD + n0 + (tc << 2)] = o;
        }
    } else if (mode == 1) {
        const int h = blockIdx.y;         // n0 = 64*h
        const int dk0 = tc << 2;
#pragma unroll
        for (int i = 0; i < 4; ++i) {
            int row = m0 + (tr << 2) + i;     // = b*L + l
            int b_ = row >> 12;
            int l_ = row & (LL - 1);
            ushort4 o;
            o.x = f2bf(acc[i][0] + bb[0]);
            o.y = f2bf(acc[i][1] + bb[1]);
            o.z = f2bf(acc[i][2] + bb[2]);
            o.w = f2bf(acc[i][3] + bb[3]);
            *(ushort4*)&Ybf[(((size_t)b_ * HH + h) * LL + l_) * DKK + dk0] = o;
        }
    } else {
        // mode 2: transpose through LDS, write [b,h,dk,L]
#pragma unroll
        for (int i = 0; i < 4; ++i)
#pragma unroll
            for (int j = 0; j < 4; ++j)
                T[(tc << 2) + j][(tr << 2) + i] = f2bf(acc[i][j] + bb[j]);
        __syncthreads();
        const int h = blockIdx.y;
        const int d = tid >> 2;           // 0..63 (dk row)
        const int c = tid & 3;            // 16-elem chunk of l
        const int b0 = m0 >> 12;          // tile spans one batch (4096%64==0)
        const int l0 = (m0 & (LL - 1)) + c * 16;
        uint4 w0 = *(const uint4*)&T[d][c * 16];
        uint4 w1 = *(const uint4*)&T[d][c * 16 + 8];
        unsigned short* dst = &Ybf[(((size_t)b0 * HH + h) * DKK + d) * LL + l0];
        *(uint4*)dst = w0;
        *(uint4*)(dst + 8) = w1;
    }
}

// ---------------------------------------------------------------------------
// flash_mfma: causal flash attention, bf16 MFMA (16x16x32), f32 accum.
// Block = (b*H+h, 64-row q-tile), 256 threads = 4 waves; wave owns 16 q-rows.
// LDS (all [64 rows][128B], XOR-swizzled byte ^= (row&7)<<4):
//   Kl: K-tile [kv][dk], Vl: V-tile transposed [dv][kv], Pl: P [q][kv] bf16.
// Softmax in registers (16-lane shfl_xor butterflies), online m/l per q-row.
// ---------------------------------------------------------------------------
__global__ __launch_bounds__(256) void flash_mfma(
    const unsigned short* __restrict__ qh, const unsigned short* __restrict__ kh,
    const unsigned short* __restrict__ vt, float* __restrict__ ctx)
{
    __shared__ unsigned short Kl[64 * 64];
    __shared__ unsigned short Vl[64 * 64];
    __shared__ unsigned short Pl[64 * 64];

    const int tid  = threadIdx.x;
    const int wave = tid >> 6;        // 0..3
    const int lane = tid & 63;
    const int lg   = lane >> 4;       // 0..3
    const int lc   = lane & 15;       // 0..15
    const int bh   = blockIdx.x;      // b*H + h  (XCD = bh%8 -> K/V L2-resident)
    const int qt   = (int)gridDim.y - 1 - (int)blockIdx.y;

    const size_t bhoff = (size_t)bh * (LL * DKK);
    const unsigned short* qb = qh + bhoff;
    const unsigned short* kb = kh + bhoff;
    const unsigned short* vb = vt + bhoff;

    // swizzled ushort index: row-major [64][128B], byte col ^= (row&7)<<4
    auto swzi = [](int row, int byte) {
        return row * 64 + ((byte ^ ((row & 7) << 4)) >> 1);
    };

    // Q A-fragments (reside in registers): A row = lc, dk = 32*c + lg*8 + i
    const int qrow = qt * 64 + wave * 16 + lc;
    const bf16x8 qf0 = *(const bf16x8*)&qb[(size_t)qrow * DKK + 0 * 32 + lg * 8];
    const bf16x8 qf1 = *(const bf16x8*)&qb[(size_t)qrow * DKK + 1 * 32 + lg * 8];

    const f32x4 vzero = {0.f, 0.f, 0.f, 0.f};
    f32x4 O[4] = {vzero, vzero, vzero, vzero};
    float m_[4] = {-1e30f, -1e30f, -1e30f, -1e30f};
    float l_[4] = {0.f, 0.f, 0.f, 0.f};
    const float scale = 0.125f;       // 1/sqrt(64)

    const int srow = tid >> 2;        // staging row 0..63
    const int sc   = tid & 3;         // staging 16-elem chunk

    for (int kt = 0; kt <= qt; ++kt) {
        __syncthreads();              // prev PV done: Kl/Vl/Pl free
        {   // stage K [kv][dk] and Vt [dv][kv] tiles (reg-staged, swizzled)
            const unsigned short* gk = &kb[(size_t)(kt * 64 + srow) * DKK + sc * 16];
            uint4 k0 = *(const uint4*)gk;
            uint4 k1 = *(const uint4*)(gk + 8);
            const unsigned short* gv = &vb[(size_t)srow * LL + kt * 64 + sc * 16];
            uint4 v0 = *(const uint4*)gv;
            uint4 v1 = *(const uint4*)(gv + 8);
            *(uint4*)&Kl[swzi(srow, sc * 32)]      = k0;
            *(uint4*)&Kl[swzi(srow, sc * 32 + 16)] = k1;
            *(uint4*)&Vl[swzi(srow, sc * 32)]      = v0;
            *(uint4*)&Vl[swzi(srow, sc * 32 + 16)] = v1;
        }
        __syncthreads();

        // S = Q K^T : 4 kv-col tiles, K=64 in 2 chunks
        f32x4 s[4];
#pragma unroll
        for (int ct = 0; ct < 4; ++ct) {
            bf16x8 kf0 = *(const bf16x8*)&Kl[swzi(16 * ct + lc, 0 * 64 + 16 * lg)];
            bf16x8 kf1 = *(const bf16x8*)&Kl[swzi(16 * ct + lc, 1 * 64 + 16 * lg)];
            f32x4 a = vzero;
            a = __builtin_amdgcn_mfma_f32_16x16x32_bf16(qf0, kf0, a, 0, 0, 0);
            a = __builtin_amdgcn_mfma_f32_16x16x32_bf16(qf1, kf1, a, 0, 0, 0);
            s[ct] = a;
        }

        // scale (+ causal mask on diagonal tile)
#pragma unroll
        for (int ct = 0; ct < 4; ++ct)
#pragma unroll
            for (int r = 0; r < 4; ++r)
                s[ct][r] *= scale;
        if (kt == qt) {
#pragma unroll
            for (int ct = 0; ct < 4; ++ct) {
                int kv = 16 * ct + lc;
#pragma unroll
                for (int r = 0; r < 4; ++r)
                    if (kv > wave * 16 + lg * 4 + r) s[ct][r] = -1e30f;
            }
        }

        // row max (4 tiles in-reg + 16-lane butterfly)
        float rmax[4], rsum[4];
#pragma unroll
        for (int r = 0; r < 4; ++r) {
            float v = fmaxf(fmaxf(s[0][r], s[1][r]), fmaxf(s[2][r], s[3][r]));
            v = fmaxf(v, __shfl_xor(v, 1));
            v = fmaxf(v, __shfl_xor(v, 2));
            v = fmaxf(v, __shfl_xor(v, 4));
            v = fmaxf(v, __shfl_xor(v, 8));
            rmax[r] = v;
        }

        // online update: rescale O and l, exponentiate P
#pragma unroll
        for (int r = 0; r < 4; ++r) {
            float mn = fmaxf(m_[r], rmax[r]);
            float f  = __expf(m_[r] - mn);
            m_[r] = mn;
            float rs = 0.f;
#pragma unroll
            for (int ct = 0; ct < 4; ++ct) {
                float p = __expf(s[ct][r] - mn);
                s[ct][r] = p;
                rs += p;
            }
            rsum[r] = rs;
            l_[r] *= f;
#pragma unroll
            for (int dt = 0; dt < 4; ++dt) O[dt][r] *= f;
        }
#pragma unroll
        for (int r = 0; r < 4; ++r) {
            float v = rsum[r];
            v += __shfl_xor(v, 1);
            v += __shfl_xor(v, 2);
            v += __shfl_xor(v, 4);
            v += __shfl_xor(v, 8);
            l_[r] += v;
        }

        // store P (bf16) to wave-private rows of Pl (swizzled)
#pragma unroll
        for (int r = 0; r < 4; ++r) {
            int row = wave * 16 + lg * 4 + r;
#pragma unroll
            for (int ct = 0; ct < 4; ++ct)
                Pl[swzi(row, 32 * ct + 2 * lc)] = f2bf(s[ct][r]);
        }

        // PV: A = P[q][kv] (row=lc), B = V[kv][dv] from Vl[dv][kv]
        bf16x8 pa0 = *(const bf16x8*)&Pl[swzi(wave * 16 + lc, 0 * 64 + 16 * lg)];
        bf16x8 pa1 = *(const bf16x8*)&Pl[swzi(wave * 16 + lc, 1 * 64 + 16 * lg)];
#pragma unroll
        for (int dt = 0; dt < 4; ++dt) {
            bf16x8 vf0 = *(const bf16x8*)&Vl[swzi(16 * dt + lc, 0 * 64 + 16 * lg)];
            bf16x8 vf1 = *(const bf16x8*)&Vl[swzi(16 * dt + lc, 1 * 64 + 16 * lg)];
            O[dt] = __builtin_amdgcn_mfma_f32_16x16x32_bf16(pa0, vf0, O[dt], 0, 0, 0);
            O[dt] = __builtin_amdgcn_mfma_f32_16x16x32_bf16(pa1, vf1, O[dt], 0, 0, 0);
        }
    }

    // epilogue: normalize, write ctx[b][l][h*64+dv] (f32)
    const int b_ = bh >> 3;
    const int h_ = bh & 7;
#pragma unroll
    for (int r = 0; r < 4; ++r) {
        float inv = 1.0f / l_[r];
        int q = qt * 64 + wave * 16 + lg * 4 + r;
        float* cp = &ctx[((size_t)b_ * LL + q) * DD + h_ * DKK + lc];
#pragma unroll
        for (int dt = 0; dt < 4; ++dt)
            cp[16 * dt] = O[dt][r] * inv;
    }
}

// ---------------------------------------------------------------------------
extern "C" void kernel_launch(void* const* d_in, const int* in_sizes, int n_in,
                              void* d_out, int out_size, void* d_ws, size_t ws_size,
                              hipStream_t stream) {
    const float* q  = (const float*)d_in[0];
    const float* k  = (const float*)d_in[1];
    const float* v  = (const float*)d_in[2];
    // d_in[3] = causal mask (tril) — semantics hard-coded in flash_mfma
    const float* Wq = (const float*)d_in[4];
    const float* bq = (const float*)d_in[5];
    const float* Wk = (const float*)d_in[6];
    const float* bk = (const float*)d_in[7];
    const float* Wv = (const float*)d_in[8];
    const float* bv = (const float*)d_in[9];
    const float* Wo = (const float*)d_in[10];
    const float* bo = (const float*)d_in[11];
    float* out = (float*)d_out;

    const size_t nBH = (size_t)BB * HH * LL * DKK;   // 4,194,304 elems
    unsigned short* qh_bf = (unsigned short*)d_ws;
    unsigned short* kh_bf = qh_bf + nBH;
    unsigned short* vt_bf = kh_bf + nBH;
    float* ctx = (float*)(vt_bf + nBH);              // ws use ~42 MB total

    dim3 pg(128, 8), pb(256);
    proj_kernel<<<pg, pb, 0, stream>>>(q, Wq, bq, nullptr, qh_bf, 1);
    proj_kernel<<<pg, pb, 0, stream>>>(k, Wk, bk, nullptr, kh_bf, 1);
    proj_kernel<<<pg, pb, 0, stream>>>(v, Wv, bv, nullptr, vt_bf, 2);

    flash_mfma<<<dim3(16, 64), 256, 0, stream>>>(qh_bf, kh_bf, vt_bf, ctx);

    proj_kernel<<<pg, pb, 0, stream>>>(ctx, Wo, bo, out, nullptr, 0);
}

// Round 13
// 324.616 us; speedup vs baseline: 2.9199x; 1.4411x over previous
//
#include <hip/hip_runtime.h>
#include <hip/hip_bf16.h>
#include <math.h>

#define BB 2
#define LL 4096
#define DD 512
#define HH 8
#define DKK 64

typedef short bf16x8 __attribute__((ext_vector_type(8)));   // 8 bf16 in 4 VGPRs
typedef float f32x4 __attribute__((ext_vector_type(4)));

__device__ __forceinline__ unsigned short f2bf(float x) {
    __hip_bfloat16 h = __float2bfloat16(x);
    return *reinterpret_cast<unsigned short*>(&h);
}

// swizzled ushort index into a [64 rows][128 B] LDS tile: byte ^= (row&7)<<4
// (validated: 0 bank conflicts in flash_mfma r10)
__device__ __forceinline__ int swzi64(int row, int byte) {
    return row * 64 + ((byte ^ ((row & 7) << 4)) >> 1);
}

// ---------------------------------------------------------------------------
// wt_kernel: pre-transpose weights. Wt[mz][n][k] = bf16(W_mz[k][n]), 4 x 512^2.
// ---------------------------------------------------------------------------
__global__ __launch_bounds__(256) void wt_kernel(
    const float* __restrict__ W0, const float* __restrict__ W1,
    const float* __restrict__ W2, const float* __restrict__ W3,
    unsigned short* __restrict__ Wt)
{
    __shared__ unsigned short T[64][72];   // 144B rows: 16B-aligned chunks, bank-spread
    const int tid = threadIdx.x;
    const int n0 = blockIdx.x * 64, k0 = blockIdx.y * 64, mz = blockIdx.z;
    const float* W = (mz == 0) ? W0 : (mz == 1) ? W1 : (mz == 2) ? W2 : W3;
    unsigned short* out = Wt + (size_t)mz * DD * DD;

#pragma unroll
    for (int it = 0; it < 2; ++it) {
        int f = tid + it * 256;           // 512 slots: 64 k-rows x 8 n-chunks
        int row = f >> 3, c8 = f & 7;
        const float* src = &W[(size_t)(k0 + row) * DD + n0 + c8 * 8];
        float4 a = *(const float4*)src, b = *(const float4*)(src + 4);
        T[c8 * 8 + 0][row] = f2bf(a.x); T[c8 * 8 + 1][row] = f2bf(a.y);
        T[c8 * 8 + 2][row] = f2bf(a.z); T[c8 * 8 + 3][row] = f2bf(a.w);
        T[c8 * 8 + 4][row] = f2bf(b.x); T[c8 * 8 + 5][row] = f2bf(b.y);
        T[c8 * 8 + 6][row] = f2bf(b.z); T[c8 * 8 + 7][row] = f2bf(b.w);
    }
    __syncthreads();
    const int d = tid >> 2, c = tid & 3;  // d: n-local, c: 16-elem k chunk
    uint4 w0 = *(const uint4*)&T[d][c * 16];
    uint4 w1 = *(const uint4*)&T[d][c * 16 + 8];
    unsigned short* dst = &out[(size_t)(n0 + d) * DD + k0 + c * 16];
    *(uint4*)dst = w0;
    *(uint4*)(dst + 8) = w1;
}

// ---------------------------------------------------------------------------
// proj_mfma: Y = X[8192,512] @ W + bias, bf16 MFMA 16x16x32, f32 accum.
// Wt is the pre-transposed bf16 weight [n][k]. 64x64 tile, BK=64, 4 waves.
// mode 0: f32 flat [M][512]; mode 1: bf16 [b,h,l,dk]; mode 2: bf16 [b,h,dk,l].
// ---------------------------------------------------------------------------
__global__ __launch_bounds__(256) void proj_mfma(
    const float* __restrict__ X, const unsigned short* __restrict__ Wt,
    const float* __restrict__ bias, float* __restrict__ Yf,
    unsigned short* __restrict__ Ybf, int mode)
{
    __shared__ unsigned short Al[64 * 64];
    __shared__ unsigned short Bl[64 * 64];

    const int tid  = threadIdx.x;
    const int wave = tid >> 6;
    const int lane = tid & 63;
    const int lg   = lane >> 4;       // 0..3
    const int lc   = lane & 15;       // 0..15
    const int m0 = blockIdx.x * 64, n0 = blockIdx.y * 64;

    const f32x4 vzero = {0.f, 0.f, 0.f, 0.f};
    f32x4 acc[4] = {vzero, vzero, vzero, vzero};

    for (int kt = 0; kt < 8; ++kt) {
        __syncthreads();              // prev tile's reads done
#pragma unroll
        for (int it = 0; it < 2; ++it) {
            int f = tid + it * 256;   // 512 slots: 64 rows x 8 chunks of 8
            int row = f >> 3, c8 = f & 7;
            const float* src = &X[(size_t)(m0 + row) * DD + kt * 64 + c8 * 8];
            float4 a = *(const float4*)src, b = *(const float4*)(src + 4);
            unsigned short h[8] = {f2bf(a.x), f2bf(a.y), f2bf(a.z), f2bf(a.w),
                                   f2bf(b.x), f2bf(b.y), f2bf(b.z), f2bf(b.w)};
            *(uint4*)&Al[swzi64(row, c8 * 16)] = *(const uint4*)h;
            const unsigned short* wsrc =
                &Wt[(size_t)(n0 + row) * DD + kt * 64 + c8 * 8];
            *(uint4*)&Bl[swzi64(row, c8 * 16)] = *(const uint4*)wsrc;
        }
        __syncthreads();

#pragma unroll
        for (int kc = 0; kc < 2; ++kc) {
            bf16x8 af = *(const bf16x8*)&Al[swzi64(wave * 16 + lc, kc * 64 + lg * 16)];
#pragma unroll
            for (int nt = 0; nt < 4; ++nt) {
                bf16x8 bf = *(const bf16x8*)&Bl[swzi64(nt * 16 + lc, kc * 64 + lg * 16)];
                acc[nt] = __builtin_amdgcn_mfma_f32_16x16x32_bf16(af, bf, acc[nt], 0, 0, 0);
            }
        }
    }

    float bv[4];
#pragma unroll
    for (int nt = 0; nt < 4; ++nt) bv[nt] = bias[n0 + nt * 16 + lc];

    if (mode == 0) {
#pragma unroll
        for (int nt = 0; nt < 4; ++nt)
#pragma unroll
            for (int r = 0; r < 4; ++r)
                Yf[(size_t)(m0 + wave * 16 + lg * 4 + r) * DD + n0 + nt * 16 + lc] =
                    acc[nt][r] + bv[nt];
    } else if (mode == 1) {
        const int h = n0 >> 6;            // = blockIdx.y
        const int b_ = m0 >> 12;          // tile never straddles batch
        const int lb = m0 & (LL - 1);
#pragma unroll
        for (int nt = 0; nt < 4; ++nt)
#pragma unroll
            for (int r = 0; r < 4; ++r) {
                int l_ = lb + wave * 16 + lg * 4 + r;
                Ybf[(((size_t)b_ * HH + h) * LL + l_) * DKK + nt * 16 + lc] =
                    f2bf(acc[nt][r] + bv[nt]);
            }
    } else {
        // mode 2: transpose via Al, write [b,h,dk,l]
        __syncthreads();                  // all waves done reading Al/Bl
#pragma unroll
        for (int nt = 0; nt < 4; ++nt)
#pragma unroll
            for (int r = 0; r < 4; ++r)
                Al[swzi64(nt * 16 + lc, (wave * 16 + lg * 4 + r) * 2)] =
                    f2bf(acc[nt][r] + bv[nt]);
        __syncthreads();
        const int h = n0 >> 6, b_ = m0 >> 12, l0 = m0 & (LL - 1);
        const int d = tid >> 2, c = tid & 3;
        uint4 w0 = *(const uint4*)&Al[swzi64(d, c * 32)];
        uint4 w1 = *(const uint4*)&Al[swzi64(d, c * 32 + 16)];
        unsigned short* dst = &Ybf[(((size_t)b_ * HH + h) * DKK + d) * LL + l0 + c * 16];
        *(uint4*)dst = w0;
        *(uint4*)(dst + 8) = w1;
    }
}

// ---------------------------------------------------------------------------
// flash_mfma: causal flash attention — UNCHANGED from the verified r10 kernel.
// ---------------------------------------------------------------------------
__global__ __launch_bounds__(256) void flash_mfma(
    const unsigned short* __restrict__ qh, const unsigned short* __restrict__ kh,
    const unsigned short* __restrict__ vt, float* __restrict__ ctx)
{
    __shared__ unsigned short Kl[64 * 64];
    __shared__ unsigned short Vl[64 * 64];
    __shared__ unsigned short Pl[64 * 64];

    const int tid  = threadIdx.x;
    const int wave = tid >> 6;        // 0..3
    const int lane = tid & 63;
    const int lg   = lane >> 4;       // 0..3
    const int lc   = lane & 15;       // 0..15
    const int bh   = blockIdx.x;      // b*H + h
    const int qt   = (int)gridDim.y - 1 - (int)blockIdx.y;

    const size_t bhoff = (size_t)bh * (LL * DKK);
    const unsigned short* qb = qh + bhoff;
    const unsigned short* kb = kh + bhoff;
    const unsigned short* vb = vt + bhoff;

    auto swzi = [](int row, int byte) {
        return row * 64 + ((byte ^ ((row & 7) << 4)) >> 1);
    };

    const int qrow = qt * 64 + wave * 16 + lc;
    const bf16x8 qf0 = *(const bf16x8*)&qb[(size_t)qrow * DKK + 0 * 32 + lg * 8];
    const bf16x8 qf1 = *(const bf16x8*)&qb[(size_t)qrow * DKK + 1 * 32 + lg * 8];

    const f32x4 vzero = {0.f, 0.f, 0.f, 0.f};
    f32x4 O[4] = {vzero, vzero, vzero, vzero};
    float m_[4] = {-1e30f, -1e30f, -1e30f, -1e30f};
    float l_[4] = {0.f, 0.f, 0.f, 0.f};
    const float scale = 0.125f;

    const int srow = tid >> 2;
    const int sc   = tid & 3;

    for (int kt = 0; kt <= qt; ++kt) {
        __syncthreads();
        {
            const unsigned short* gk = &kb[(size_t)(kt * 64 + srow) * DKK + sc * 16];
            uint4 k0 = *(const uint4*)gk;
            uint4 k1 = *(const uint4*)(gk + 8);
            const unsigned short* gv = &vb[(size_t)srow * LL + kt * 64 + sc * 16];
            uint4 v0 = *(const uint4*)gv;
            uint4 v1 = *(const uint4*)(gv + 8);
            *(uint4*)&Kl[swzi(srow, sc * 32)]      = k0;
            *(uint4*)&Kl[swzi(srow, sc * 32 + 16)] = k1;
            *(uint4*)&Vl[swzi(srow, sc * 32)]      = v0;
            *(uint4*)&Vl[swzi(srow, sc * 32 + 16)] = v1;
        }
        __syncthreads();

        f32x4 s[4];
#pragma unroll
        for (int ct = 0; ct < 4; ++ct) {
            bf16x8 kf0 = *(const bf16x8*)&Kl[swzi(16 * ct + lc, 0 * 64 + 16 * lg)];
            bf16x8 kf1 = *(const bf16x8*)&Kl[swzi(16 * ct + lc, 1 * 64 + 16 * lg)];
            f32x4 a = vzero;
            a = __builtin_amdgcn_mfma_f32_16x16x32_bf16(qf0, kf0, a, 0, 0, 0);
            a = __builtin_amdgcn_mfma_f32_16x16x32_bf16(qf1, kf1, a, 0, 0, 0);
            s[ct] = a;
        }

#pragma unroll
        for (int ct = 0; ct < 4; ++ct)
#pragma unroll
            for (int r = 0; r < 4; ++r)
                s[ct][r] *= scale;
        if (kt == qt) {
#pragma unroll
            for (int ct = 0; ct < 4; ++ct) {
                int kv = 16 * ct + lc;
#pragma unroll
                for (int r = 0; r < 4; ++r)
                    if (kv > wave * 16 + lg * 4 + r) s[ct][r] = -1e30f;
            }
        }

        float rmax[4], rsum[4];
#pragma unroll
        for (int r = 0; r < 4; ++r) {
            float v = fmaxf(fmaxf(s[0][r], s[1][r]), fmaxf(s[2][r], s[3][r]));
            v = fmaxf(v, __shfl_xor(v, 1));
            v = fmaxf(v, __shfl_xor(v, 2));
            v = fmaxf(v, __shfl_xor(v, 4));
            v = fmaxf(v, __shfl_xor(v, 8));
            rmax[r] = v;
        }

#pragma unroll
        for (int r = 0; r < 4; ++r) {
            float mn = fmaxf(m_[r], rmax[r]);
            float f  = __expf(m_[r] - mn);
            m_[r] = mn;
            float rs = 0.f;
#pragma unroll
            for (int ct = 0; ct < 4; ++ct) {
                float p = __expf(s[ct][r] - mn);
                s[ct][r] = p;
                rs += p;
            }
            rsum[r] = rs;
            l_[r] *= f;
#pragma unroll
            for (int dt = 0; dt < 4; ++dt) O[dt][r] *= f;
        }
#pragma unroll
        for (int r = 0; r < 4; ++r) {
            float v = rsum[r];
            v += __shfl_xor(v, 1);
            v += __shfl_xor(v, 2);
            v += __shfl_xor(v, 4);
            v += __shfl_xor(v, 8);
            l_[r] += v;
        }

#pragma unroll
        for (int r = 0; r < 4; ++r) {
            int row = wave * 16 + lg * 4 + r;
#pragma unroll
            for (int ct = 0; ct < 4; ++ct)
                Pl[swzi(row, 32 * ct + 2 * lc)] = f2bf(s[ct][r]);
        }

        bf16x8 pa0 = *(const bf16x8*)&Pl[swzi(wave * 16 + lc, 0 * 64 + 16 * lg)];
        bf16x8 pa1 = *(const bf16x8*)&Pl[swzi(wave * 16 + lc, 1 * 64 + 16 * lg)];
#pragma unroll
        for (int dt = 0; dt < 4; ++dt) {
            bf16x8 vf0 = *(const bf16x8*)&Vl[swzi(16 * dt + lc, 0 * 64 + 16 * lg)];
            bf16x8 vf1 = *(const bf16x8*)&Vl[swzi(16 * dt + lc, 1 * 64 + 16 * lg)];
            O[dt] = __builtin_amdgcn_mfma_f32_16x16x32_bf16(pa0, vf0, O[dt], 0, 0, 0);
            O[dt] = __builtin_amdgcn_mfma_f32_16x16x32_bf16(pa1, vf1, O[dt], 0, 0, 0);
        }
    }

    const int b_ = bh >> 3;
    const int h_ = bh & 7;
#pragma unroll
    for (int r = 0; r < 4; ++r) {
        float inv = 1.0f / l_[r];
        int q = qt * 64 + wave * 16 + lg * 4 + r;
        float* cp = &ctx[((size_t)b_ * LL + q) * DD + h_ * DKK + lc];
#pragma unroll
        for (int dt = 0; dt < 4; ++dt)
            cp[16 * dt] = O[dt][r] * inv;
    }
}

// ---------------------------------------------------------------------------
extern "C" void kernel_launch(void* const* d_in, const int* in_sizes, int n_in,
                              void* d_out, int out_size, void* d_ws, size_t ws_size,
                              hipStream_t stream) {
    const float* q  = (const float*)d_in[0];
    const float* k  = (const float*)d_in[1];
    const float* v  = (const float*)d_in[2];
    // d_in[3] = causal mask (tril) — semantics hard-coded in flash_mfma
    const float* Wq = (const float*)d_in[4];
    const float* bq = (const float*)d_in[5];
    const float* Wk = (const float*)d_in[6];
    const float* bk = (const float*)d_in[7];
    const float* Wv = (const float*)d_in[8];
    const float* bv = (const float*)d_in[9];
    const float* Wo = (const float*)d_in[10];
    const float* bo = (const float*)d_in[11];
    float* out = (float*)d_out;

    const size_t nBH = (size_t)BB * HH * LL * DKK;   // 4,194,304 elems
    unsigned short* qh_bf = (unsigned short*)d_ws;
    unsigned short* kh_bf = qh_bf + nBH;
    unsigned short* vt_bf = kh_bf + nBH;
    float* ctx = (float*)(vt_bf + nBH);              // 16.8 MB
    unsigned short* wt4 = (unsigned short*)(ctx + nBH);  // 4 x 512KB bf16, total ~46 MB

    unsigned short* wtq = wt4;
    unsigned short* wtk = wt4 + (size_t)DD * DD;
    unsigned short* wtv = wt4 + (size_t)2 * DD * DD;
    unsigned short* wto = wt4 + (size_t)3 * DD * DD;

    wt_kernel<<<dim3(8, 8, 4), 256, 0, stream>>>(Wq, Wk, Wv, Wo, wt4);

    dim3 pg(128, 8), pb(256);
    proj_mfma<<<pg, pb, 0, stream>>>(q, wtq, bq, nullptr, qh_bf, 1);
    proj_mfma<<<pg, pb, 0, stream>>>(k, wtk, bk, nullptr, kh_bf, 1);
    proj_mfma<<<pg, pb, 0, stream>>>(v, wtv, bv, nullptr, vt_bf, 2);

    flash_mfma<<<dim3(16, 64), 256, 0, stream>>>(qh_bf, kh_bf, vt_bf, ctx);

    proj_mfma<<<pg, pb, 0, stream>>>(ctx, wto, bo, out, nullptr, 0);
}

// Round 14
// 320.983 us; speedup vs baseline: 2.9530x; 1.0113x over previous
//
#include <hip/hip_runtime.h>
#include <hip/hip_bf16.h>
#include <math.h>

#define BB 2
#define LL 4096
#define DD 512
#define HH 8
#define DKK 64

typedef short bf16x8 __attribute__((ext_vector_type(8)));   // 8 bf16 in 4 VGPRs
typedef float f32x4 __attribute__((ext_vector_type(4)));

__device__ __forceinline__ unsigned short f2bf(float x) {
    __hip_bfloat16 h = __float2bfloat16(x);
    return *reinterpret_cast<unsigned short*>(&h);
}

// swizzled ushort index into a [64 rows][128 B] tile: byte ^= (row&7)<<4
// (validated: 0 bank conflicts in flash_mfma r10/r13)
__device__ __forceinline__ int swzi64(int row, int byte) {
    return row * 64 + ((byte ^ ((row & 7) << 4)) >> 1);
}

// ---------------------------------------------------------------------------
// cvt_tile: X f32 [8192][512] -> bf16 tiled-swizzled images.
// Tile (mt,kt) = 64 rows x 64 k, stored as the 8KB swizzled LDS image at
// out[(mt*8+kt)*4096]. proj_mfma then stages it with pure linear copies.
// ---------------------------------------------------------------------------
__global__ __launch_bounds__(256) void cvt_tile(
    const float* __restrict__ X, unsigned short* __restrict__ out)
{
    const int tid = threadIdx.x;
    const int mt = blockIdx.x, kt = blockIdx.y;
    const int row = tid >> 2, c = tid & 3;          // row 0..63, 16-elem chunk
    const float* src = &X[(size_t)(mt * 64 + row) * DD + kt * 64 + c * 16];
    float4 a = *(const float4*)src;
    float4 b = *(const float4*)(src + 4);
    float4 e = *(const float4*)(src + 8);
    float4 g = *(const float4*)(src + 12);
    unsigned short h0[8] = {f2bf(a.x), f2bf(a.y), f2bf(a.z), f2bf(a.w),
                            f2bf(b.x), f2bf(b.y), f2bf(b.z), f2bf(b.w)};
    unsigned short h1[8] = {f2bf(e.x), f2bf(e.y), f2bf(e.z), f2bf(e.w),
                            f2bf(g.x), f2bf(g.y), f2bf(g.z), f2bf(g.w)};
    unsigned short* t = out + ((size_t)mt * 8 + kt) * 4096;
    *(uint4*)&t[swzi64(row, c * 32)]      = *(const uint4*)h0;
    *(uint4*)&t[swzi64(row, c * 32 + 16)] = *(const uint4*)h1;
}

// ---------------------------------------------------------------------------
// wt_kernel: weights -> bf16 transposed tiled-swizzled images.
// Wt[mz] tile (nt,kt): Wt_elem[n][k] = W[k][n], stored as swizzled 8KB image.
// ---------------------------------------------------------------------------
__global__ __launch_bounds__(256) void wt_kernel(
    const float* __restrict__ W0, const float* __restrict__ W1,
    const float* __restrict__ W2, const float* __restrict__ W3,
    unsigned short* __restrict__ Wt)
{
    __shared__ unsigned short T[64][72];   // 144B rows: 16B chunks, bank-spread
    const int tid = threadIdx.x;
    const int n0 = blockIdx.x * 64, k0 = blockIdx.y * 64, mz = blockIdx.z;
    const float* W = (mz == 0) ? W0 : (mz == 1) ? W1 : (mz == 2) ? W2 : W3;
    unsigned short* out = Wt + (size_t)mz * DD * DD;

#pragma unroll
    for (int it = 0; it < 2; ++it) {
        int f = tid + it * 256;           // 512 slots: 64 k-rows x 8 n-chunks
        int row = f >> 3, c8 = f & 7;
        const float* src = &W[(size_t)(k0 + row) * DD + n0 + c8 * 8];
        float4 a = *(const float4*)src, b = *(const float4*)(src + 4);
        T[c8 * 8 + 0][row] = f2bf(a.x); T[c8 * 8 + 1][row] = f2bf(a.y);
        T[c8 * 8 + 2][row] = f2bf(a.z); T[c8 * 8 + 3][row] = f2bf(a.w);
        T[c8 * 8 + 4][row] = f2bf(b.x); T[c8 * 8 + 5][row] = f2bf(b.y);
        T[c8 * 8 + 6][row] = f2bf(b.z); T[c8 * 8 + 7][row] = f2bf(b.w);
    }
    __syncthreads();
    const int d = tid >> 2, c = tid & 3;  // d: n-local row, c: 16-elem k chunk
    uint4 w0 = *(const uint4*)&T[d][c * 16];
    uint4 w1 = *(const uint4*)&T[d][c * 16 + 8];
    unsigned short* t = out + ((size_t)blockIdx.x * 8 + blockIdx.y) * 4096;
    *(uint4*)&t[swzi64(d, c * 32)]      = w0;
    *(uint4*)&t[swzi64(d, c * 32 + 16)] = w1;
}

// ---------------------------------------------------------------------------
// proj_mfma: Y = X @ W + bias, bf16 MFMA 16x16x32, f32 accum.
// Xt/Wt are pre-swizzled tiled bf16 images; staging = pure linear 16B copies
// (conflict-free); fragment reads/epilogues identical to the r13-verified code.
// mode 0: f32 flat [M][512]; mode 1: bf16 [b,h,l,dk]; mode 2: bf16 [b,h,dk,l].
// ---------------------------------------------------------------------------
__global__ __launch_bounds__(256) void proj_mfma(
    const unsigned short* __restrict__ Xt, const unsigned short* __restrict__ Wt,
    const float* __restrict__ bias, float* __restrict__ Yf,
    unsigned short* __restrict__ Ybf, int mode)
{
    __shared__ unsigned short Al[64 * 64];
    __shared__ unsigned short Bl[64 * 64];

    const int tid  = threadIdx.x;
    const int wave = tid >> 6;
    const int lane = tid & 63;
    const int lg   = lane >> 4;       // 0..3
    const int lc   = lane & 15;       // 0..15
    const int m0 = blockIdx.x * 64, n0 = blockIdx.y * 64;

    const unsigned short* Abase = Xt + (size_t)(m0 >> 6) * 8 * 4096;
    const unsigned short* Bbase = Wt + (size_t)(n0 >> 6) * 8 * 4096;

    const f32x4 vzero = {0.f, 0.f, 0.f, 0.f};
    f32x4 acc[4] = {vzero, vzero, vzero, vzero};

    for (int kt = 0; kt < 8; ++kt) {
        __syncthreads();              // prev tile's reads done
        {   // linear copy of the pre-swizzled 8KB images (16B/lane stride)
            const unsigned short* At = Abase + kt * 4096;
            const unsigned short* Bt = Bbase + kt * 4096;
            uint4 a0 = *(const uint4*)&At[tid * 8];
            uint4 a1 = *(const uint4*)&At[2048 + tid * 8];
            uint4 b0 = *(const uint4*)&Bt[tid * 8];
            uint4 b1 = *(const uint4*)&Bt[2048 + tid * 8];
            *(uint4*)&Al[tid * 8]        = a0;
            *(uint4*)&Al[2048 + tid * 8] = a1;
            *(uint4*)&Bl[tid * 8]        = b0;
            *(uint4*)&Bl[2048 + tid * 8] = b1;
        }
        __syncthreads();

#pragma unroll
        for (int kc = 0; kc < 2; ++kc) {
            bf16x8 af = *(const bf16x8*)&Al[swzi64(wave * 16 + lc, kc * 64 + lg * 16)];
#pragma unroll
            for (int nt = 0; nt < 4; ++nt) {
                bf16x8 bf = *(const bf16x8*)&Bl[swzi64(nt * 16 + lc, kc * 64 + lg * 16)];
                acc[nt] = __builtin_amdgcn_mfma_f32_16x16x32_bf16(af, bf, acc[nt], 0, 0, 0);
            }
        }
    }

    float bv[4];
#pragma unroll
    for (int nt = 0; nt < 4; ++nt) bv[nt] = bias[n0 + nt * 16 + lc];

    if (mode == 0) {
#pragma unroll
        for (int nt = 0; nt < 4; ++nt)
#pragma unroll
            for (int r = 0; r < 4; ++r)
                Yf[(size_t)(m0 + wave * 16 + lg * 4 + r) * DD + n0 + nt * 16 + lc] =
                    acc[nt][r] + bv[nt];
    } else if (mode == 1) {
        const int h = n0 >> 6;            // = blockIdx.y
        const int b_ = m0 >> 12;          // tile never straddles batch
        const int lb = m0 & (LL - 1);
#pragma unroll
        for (int nt = 0; nt < 4; ++nt)
#pragma unroll
            for (int r = 0; r < 4; ++r) {
                int l_ = lb + wave * 16 + lg * 4 + r;
                Ybf[(((size_t)b_ * HH + h) * LL + l_) * DKK + nt * 16 + lc] =
                    f2bf(acc[nt][r] + bv[nt]);
            }
    } else {
        // mode 2: transpose via Al, write [b,h,dk,l]
        __syncthreads();                  // all waves done reading Al/Bl
#pragma unroll
        for (int nt = 0; nt < 4; ++nt)
#pragma unroll
            for (int r = 0; r < 4; ++r)
                Al[swzi64(nt * 16 + lc, (wave * 16 + lg * 4 + r) * 2)] =
                    f2bf(acc[nt][r] + bv[nt]);
        __syncthreads();
        const int h = n0 >> 6, b_ = m0 >> 12, l0 = m0 & (LL - 1);
        const int d = tid >> 2, c = tid & 3;
        uint4 w0 = *(const uint4*)&Al[swzi64(d, c * 32)];
        uint4 w1 = *(const uint4*)&Al[swzi64(d, c * 32 + 16)];
        unsigned short* dst = &Ybf[(((size_t)b_ * HH + h) * DKK + d) * LL + l0 + c * 16];
        *(uint4*)dst = w0;
        *(uint4*)(dst + 8) = w1;
    }
}

// ---------------------------------------------------------------------------
// flash_mfma: causal flash attention — UNCHANGED from the verified r10 kernel.
// ---------------------------------------------------------------------------
__global__ __launch_bounds__(256) void flash_mfma(
    const unsigned short* __restrict__ qh, const unsigned short* __restrict__ kh,
    const unsigned short* __restrict__ vt, float* __restrict__ ctx)
{
    __shared__ unsigned short Kl[64 * 64];
    __shared__ unsigned short Vl[64 * 64];
    __shared__ unsigned short Pl[64 * 64];

    const int tid  = threadIdx.x;
    const int wave = tid >> 6;        // 0..3
    const int lane = tid & 63;
    const int lg   = lane >> 4;       // 0..3
    const int lc   = lane & 15;       // 0..15
    const int bh   = blockIdx.x;      // b*H + h
    const int qt   = (int)gridDim.y - 1 - (int)blockIdx.y;

    const size_t bhoff = (size_t)bh * (LL * DKK);
    const unsigned short* qb = qh + bhoff;
    const unsigned short* kb = kh + bhoff;
    const unsigned short* vb = vt + bhoff;

    auto swzi = [](int row, int byte) {
        return row * 64 + ((byte ^ ((row & 7) << 4)) >> 1);
    };

    const int qrow = qt * 64 + wave * 16 + lc;
    const bf16x8 qf0 = *(const bf16x8*)&qb[(size_t)qrow * DKK + 0 * 32 + lg * 8];
    const bf16x8 qf1 = *(const bf16x8*)&qb[(size_t)qrow * DKK + 1 * 32 + lg * 8];

    const f32x4 vzero = {0.f, 0.f, 0.f, 0.f};
    f32x4 O[4] = {vzero, vzero, vzero, vzero};
    float m_[4] = {-1e30f, -1e30f, -1e30f, -1e30f};
    float l_[4] = {0.f, 0.f, 0.f, 0.f};
    const float scale = 0.125f;

    const int srow = tid >> 2;
    const int sc   = tid & 3;

    for (int kt = 0; kt <= qt; ++kt) {
        __syncthreads();
        {
            const unsigned short* gk = &kb[(size_t)(kt * 64 + srow) * DKK + sc * 16];
            uint4 k0 = *(const uint4*)gk;
            uint4 k1 = *(const uint4*)(gk + 8);
            const unsigned short* gv = &vb[(size_t)srow * LL + kt * 64 + sc * 16];
            uint4 v0 = *(const uint4*)gv;
            uint4 v1 = *(const uint4*)(gv + 8);
            *(uint4*)&Kl[swzi(srow, sc * 32)]      = k0;
            *(uint4*)&Kl[swzi(srow, sc * 32 + 16)] = k1;
            *(uint4*)&Vl[swzi(srow, sc * 32)]      = v0;
            *(uint4*)&Vl[swzi(srow, sc * 32 + 16)] = v1;
        }
        __syncthreads();

        f32x4 s[4];
#pragma unroll
        for (int ct = 0; ct < 4; ++ct) {
            bf16x8 kf0 = *(const bf16x8*)&Kl[swzi(16 * ct + lc, 0 * 64 + 16 * lg)];
            bf16x8 kf1 = *(const bf16x8*)&Kl[swzi(16 * ct + lc, 1 * 64 + 16 * lg)];
            f32x4 a = vzero;
            a = __builtin_amdgcn_mfma_f32_16x16x32_bf16(qf0, kf0, a, 0, 0, 0);
            a = __builtin_amdgcn_mfma_f32_16x16x32_bf16(qf1, kf1, a, 0, 0, 0);
            s[ct] = a;
        }

#pragma unroll
        for (int ct = 0; ct < 4; ++ct)
#pragma unroll
            for (int r = 0; r < 4; ++r)
                s[ct][r] *= scale;
        if (kt == qt) {
#pragma unroll
            for (int ct = 0; ct < 4; ++ct) {
                int kv = 16 * ct + lc;
#pragma unroll
                for (int r = 0; r < 4; ++r)
                    if (kv > wave * 16 + lg * 4 + r) s[ct][r] = -1e30f;
            }
        }

        float rmax[4], rsum[4];
#pragma unroll
        for (int r = 0; r < 4; ++r) {
            float v = fmaxf(fmaxf(s[0][r], s[1][r]), fmaxf(s[2][r], s[3][r]));
            v = fmaxf(v, __shfl_xor(v, 1));
            v = fmaxf(v, __shfl_xor(v, 2));
            v = fmaxf(v, __shfl_xor(v, 4));
            v = fmaxf(v, __shfl_xor(v, 8));
            rmax[r] = v;
        }

#pragma unroll
        for (int r = 0; r < 4; ++r) {
            float mn = fmaxf(m_[r], rmax[r]);
            float f  = __expf(m_[r] - mn);
            m_[r] = mn;
            float rs = 0.f;
#pragma unroll
            for (int ct = 0; ct < 4; ++ct) {
                float p = __expf(s[ct][r] - mn);
                s[ct][r] = p;
                rs += p;
            }
            rsum[r] = rs;
            l_[r] *= f;
#pragma unroll
            for (int dt = 0; dt < 4; ++dt) O[dt][r] *= f;
        }
#pragma unroll
        for (int r = 0; r < 4; ++r) {
            float v = rsum[r];
            v += __shfl_xor(v, 1);
            v += __shfl_xor(v, 2);
            v += __shfl_xor(v, 4);
            v += __shfl_xor(v, 8);
            l_[r] += v;
        }

#pragma unroll
        for (int r = 0; r < 4; ++r) {
            int row = wave * 16 + lg * 4 + r;
#pragma unroll
            for (int ct = 0; ct < 4; ++ct)
                Pl[swzi(row, 32 * ct + 2 * lc)] = f2bf(s[ct][r]);
        }

        bf16x8 pa0 = *(const bf16x8*)&Pl[swzi(wave * 16 + lc, 0 * 64 + 16 * lg)];
        bf16x8 pa1 = *(const bf16x8*)&Pl[swzi(wave * 16 + lc, 1 * 64 + 16 * lg)];
#pragma unroll
        for (int dt = 0; dt < 4; ++dt) {
            bf16x8 vf0 = *(const bf16x8*)&Vl[swzi(16 * dt + lc, 0 * 64 + 16 * lg)];
            bf16x8 vf1 = *(const bf16x8*)&Vl[swzi(16 * dt + lc, 1 * 64 + 16 * lg)];
            O[dt] = __builtin_amdgcn_mfma_f32_16x16x32_bf16(pa0, vf0, O[dt], 0, 0, 0);
            O[dt] = __builtin_amdgcn_mfma_f32_16x16x32_bf16(pa1, vf1, O[dt], 0, 0, 0);
        }
    }

    const int b_ = bh >> 3;
    const int h_ = bh & 7;
#pragma unroll
    for (int r = 0; r < 4; ++r) {
        float inv = 1.0f / l_[r];
        int q = qt * 64 + wave * 16 + lg * 4 + r;
        float* cp = &ctx[((size_t)b_ * LL + q) * DD + h_ * DKK + lc];
#pragma unroll
        for (int dt = 0; dt < 4; ++dt)
            cp[16 * dt] = O[dt][r] * inv;
    }
}

// ---------------------------------------------------------------------------
extern "C" void kernel_launch(void* const* d_in, const int* in_sizes, int n_in,
                              void* d_out, int out_size, void* d_ws, size_t ws_size,
                              hipStream_t stream) {
    const float* q  = (const float*)d_in[0];
    const float* k  = (const float*)d_in[1];
    const float* v  = (const float*)d_in[2];
    // d_in[3] = causal mask (tril) — semantics hard-coded in flash_mfma
    const float* Wq = (const float*)d_in[4];
    const float* bq = (const float*)d_in[5];
    const float* Wk = (const float*)d_in[6];
    const float* bk = (const float*)d_in[7];
    const float* Wv = (const float*)d_in[8];
    const float* bv = (const float*)d_in[9];
    const float* Wo = (const float*)d_in[10];
    const float* bo = (const float*)d_in[11];
    float* out = (float*)d_out;

    const size_t nBH = (size_t)BB * HH * LL * DKK;   // 4,194,304 elems
    unsigned short* qh_bf = (unsigned short*)d_ws;               // 8.4 MB
    unsigned short* kh_bf = qh_bf + nBH;                         // 8.4 MB
    unsigned short* vt_bf = kh_bf + nBH;                         // 8.4 MB
    float* ctx = (float*)(vt_bf + nBH);                          // 16.8 MB
    unsigned short* wt4 = (unsigned short*)(ctx + nBH);          // 2 MB
    unsigned short* xbf = wt4 + (size_t)4 * DD * DD;             // 8.4 MB (reused 4x)
    // total ~52.4 MB, all rewritten every call

    unsigned short* wtq = wt4;
    unsigned short* wtk = wt4 + (size_t)DD * DD;
    unsigned short* wtv = wt4 + (size_t)2 * DD * DD;
    unsigned short* wto = wt4 + (size_t)3 * DD * DD;

    wt_kernel<<<dim3(8, 8, 4), 256, 0, stream>>>(Wq, Wk, Wv, Wo, wt4);

    dim3 cg(128, 8), pg(128, 8), pb(256);
    cvt_tile<<<cg, pb, 0, stream>>>(q, xbf);
    proj_mfma<<<pg, pb, 0, stream>>>(xbf, wtq, bq, nullptr, qh_bf, 1);
    cvt_tile<<<cg, pb, 0, stream>>>(k, xbf);
    proj_mfma<<<pg, pb, 0, stream>>>(xbf, wtk, bk, nullptr, kh_bf, 1);
    cvt_tile<<<cg, pb, 0, stream>>>(v, xbf);
    proj_mfma<<<pg, pb, 0, stream>>>(xbf, wtv, bv, nullptr, vt_bf, 2);

    flash_mfma<<<dim3(16, 64), 256, 0, stream>>>(qh_bf, kh_bf, vt_bf, ctx);

    cvt_tile<<<cg, pb, 0, stream>>>(ctx, xbf);
    proj_mfma<<<pg, pb, 0, stream>>>(xbf, wto, bo, out, nullptr, 0);
}